// Round 5
// baseline (165.527 us; speedup 1.0000x reference)
//
#include <hip/hip_runtime.h>

#define PI_F 3.14159265358979f

typedef unsigned int  uint32;
typedef unsigned short ushort16;

// ---------------------------------------------------------------------------
// complex / bf16 helpers
// ---------------------------------------------------------------------------
__device__ __forceinline__ float2 cmul(float2 a, float2 b) {
    return make_float2(a.x * b.x - a.y * b.y, a.x * b.y + a.y * b.x);
}
__device__ __forceinline__ float2 cadd(float2 a, float2 b) { return make_float2(a.x + b.x, a.y + b.y); }
__device__ __forceinline__ float2 csub(float2 a, float2 b) { return make_float2(a.x - b.x, a.y - b.y); }
__device__ __forceinline__ float2 shflx(float2 v, int m) {
    return make_float2(__shfl_xor(v.x, m, 64), __shfl_xor(v.y, m, 64));
}
__device__ __forceinline__ float2 shfli(float2 v, int src) {
    return make_float2(__shfl(v.x, src, 64), __shfl(v.y, src, 64));
}
__device__ __forceinline__ int brev6(int x) { return (int)(__brev((unsigned)x) >> 26); }

__device__ __forceinline__ uint32 bfu(float x) {              // fp32 -> bf16 (RNE), low 16
    uint32 u = __float_as_uint(x);
    return (u + 0x7FFFu + ((u >> 16) & 1u)) >> 16;
}
__device__ __forceinline__ uint32 packbf2(float2 v) { return bfu(v.x) | (bfu(v.y) << 16); }
__device__ __forceinline__ float2 unpackbf2(uint32 u) {
    return make_float2(__uint_as_float(u << 16), __uint_as_float(u & 0xFFFF0000u));
}
__device__ __forceinline__ float bf2f(ushort16 u) { return __uint_as_float((uint32)u << 16); }

// DPP cross-lane exchange (no LDS pipe): xor1 = quad_perm[1,0,3,2] (0xB1),
// xor2 = quad_perm[2,3,0,1] (0x4E), xor8 = row_ror:8 (0x128).
template<int CTRL>
__device__ __forceinline__ float dpp1(float x) {
    return __builtin_bit_cast(float, __builtin_amdgcn_update_dpp(
        0, __builtin_bit_cast(int, x), CTRL, 0xF, 0xF, true));
}
template<int CTRL>
__device__ __forceinline__ float2 dppx(float2 v) {
    return make_float2(dpp1<CTRL>(v.x), dpp1<CTRL>(v.y));
}

// ds_swizzle xor-4 (BitMode: xor_mask=4, and_mask=0x1F).
__device__ __forceinline__ float swz4(float x) {
    return __int_as_float(__builtin_amdgcn_ds_swizzle(__float_as_int(x), 0x101F));
}

// Per-lane twiddles for the 6 shuffle DIF stages (m = 32,16,8,4,2,1).
// Stages 0,1 (m=32,16): orientation-free permlane-swap butterfly
//   sg[t] = up ? -2 : 0,  d = (v[l|m] + v[l&~m]) + sg*v
// Stages 2..5: partner-exchange form: sg[t] = up ? -1 : +1, d = sg*v + p.
template<bool INV>
__device__ __forceinline__ void tw_init(int lane, float2* w, float* sg) {
#pragma unroll
    for (int t = 0; t < 6; ++t) {
        int m = 32 >> t;
        bool up = (lane & m) != 0;
        int pos = lane & (m - 1);
        float ang = (INV ? PI_F : -PI_F) * (float)pos / (float)m;
        float sn, cs;
        __sincosf(ang, &sn, &cs);
        w[t]  = up ? make_float2(cs, sn) : make_float2(1.f, 0.f);
        sg[t] = (t < 2) ? (up ? -2.f : 0.f) : (up ? -1.f : 1.f);
    }
}

// 64-pt DIF FFT across the wave, 1 elem/lane. Natural in; out: lane l holds X[brev6(l)].
__device__ __forceinline__ float2 fft64s(float2 v, const float2* w, const float* sg) {
#if __has_builtin(__builtin_amdgcn_permlane32_swap) && __has_builtin(__builtin_amdgcn_permlane16_swap)
    {   // stage 0: m=32 via permlane32_swap (VALU pipe)
        auto rx = __builtin_amdgcn_permlane32_swap(__float_as_uint(v.x), __float_as_uint(v.x), false, false);
        auto ry = __builtin_amdgcn_permlane32_swap(__float_as_uint(v.y), __float_as_uint(v.y), false, false);
        float2 d = make_float2(
            fmaf(sg[0], v.x, __uint_as_float(rx[0]) + __uint_as_float(rx[1])),
            fmaf(sg[0], v.y, __uint_as_float(ry[0]) + __uint_as_float(ry[1])));
        v = cmul(d, w[0]);
    }
    {   // stage 1: m=16 via permlane16_swap
        auto rx = __builtin_amdgcn_permlane16_swap(__float_as_uint(v.x), __float_as_uint(v.x), false, false);
        auto ry = __builtin_amdgcn_permlane16_swap(__float_as_uint(v.y), __float_as_uint(v.y), false, false);
        float2 d = make_float2(
            fmaf(sg[1], v.x, __uint_as_float(rx[0]) + __uint_as_float(rx[1])),
            fmaf(sg[1], v.y, __uint_as_float(ry[0]) + __uint_as_float(ry[1])));
        v = cmul(d, w[1]);
    }
#else
    {   float2 p = shflx(v, 32); float s0 = 1.0f + sg[0];
        float2 d = make_float2(fmaf(s0, v.x, p.x), fmaf(s0, v.y, p.y));
        v = cmul(d, w[0]);
    }
    {   float2 p = shflx(v, 16); float s1 = 1.0f + sg[1];
        float2 d = make_float2(fmaf(s1, v.x, p.x), fmaf(s1, v.y, p.y));
        v = cmul(d, w[1]);
    }
#endif
    {   // stage 2: m=8 (DPP row_ror:8)
        float2 p = dppx<0x128>(v);
        float2 d = make_float2(fmaf(sg[2], v.x, p.x), fmaf(sg[2], v.y, p.y));
        v = cmul(d, w[2]);
    }
    {   // stage 3: m=4 (ds_swizzle xor4)
        float2 p = make_float2(swz4(v.x), swz4(v.y));
        float2 d = make_float2(fmaf(sg[3], v.x, p.x), fmaf(sg[3], v.y, p.y));
        v = cmul(d, w[3]);
    }
    {   // stage 4: m=2 (DPP)
        float2 p = dppx<0x4E>(v);
        float2 d = make_float2(fmaf(sg[4], v.x, p.x), fmaf(sg[4], v.y, p.y));
        v = cmul(d, w[4]);
    }
    {   // stage 5: m=1 (DPP)
        float2 p = dppx<0xB1>(v);
        float2 d = make_float2(fmaf(sg[5], v.x, p.x), fmaf(sg[5], v.y, p.y));
        v = cmul(d, w[5]);
    }
    return v;
}

// XOR-swizzled LDS index for the 256x64 bf16c half-spectrum (stride 66 words).
// Key on (r>>4)&3 so rows r, r+64, r+128, r+192 (col-FFT lanes l, l+16 groups)
// land on different bank halves. Bijective per row; bit0 untouched (uint2 ok).
__device__ __forceinline__ int s66(int r, int c) {
    return r * 66 + (c ^ (((r >> 4) & 3) << 4));
}

// ---------------------------------------------------------------------------
// kfft body (one block per (c1,c2) image, 8 waves): rfft2(128x128) in regs +
// frequency-domain D4 symmetrization -> real K (128 x 64) in bf16.
// ---------------------------------------------------------------------------
__device__ void kfft_body(const float* __restrict__ kin, ushort16* __restrict__ kout,
                          float2* X, int img) {
    int lane = threadIdx.x & 63, wv = threadIdx.x >> 6;   // 8 waves
    float2 w[6]; float sg[6];
    tw_init<false>(lane, w, sg);
    int b6 = brev6(lane);
    float sn, cs;
    __sincosf(-PI_F * (float)lane * (1.0f / 64.0f), &sn, &cs);
    float2 w64 = make_float2(cs, sn);           // col intra-stage twiddle (lane-based)
    __sincosf(-PI_F * (float)b6 * (1.0f / 64.0f), &sn, &cs);
    float2 wub = make_float2(cs, sn);           // rfft unpack twiddle at k = b6
    const float2* in2 = (const float2*)(kin + (size_t)img * 16384);
    int gm2 = brev6((64 - b6) & 63);            // lane holding Z[(64-b6)&63]
    // ---- row phase: 16 rows per wave, rfft128 via cfft64 in regs ----
#pragma unroll 2
    for (int rr = 0; rr < 16; ++rr) {
        int r = wv * 16 + rr;
        float2 z = in2[r * 64 + lane];
        z = fft64s(z, w, sg);                   // lane l holds Z[brev6(l)]
        float2 zm = shfli(z, gm2);
        float ar = z.x + zm.x, ai = z.y - zm.y;
        float br = z.x - zm.x, bi = z.y + zm.y;
        float p = wub.x * br - wub.y * bi, q = wub.x * bi + wub.y * br;
        X[r * 65 + b6] = make_float2(0.5f * (ar + q), 0.5f * (ai - p));
    }
    __syncthreads();
    // ---- col phase: 8 cols per wave, cfft128 (2 regs/lane) ----
    float2 c0[8], c1[8];
#pragma unroll
    for (int cc = 0; cc < 8; ++cc) {
        int k = wv * 8 + cc;
        c0[cc] = X[lane * 65 + k];
        c1[cc] = X[(lane + 64) * 65 + k];
    }
    __syncthreads();                            // all X reads done; reuse LDS as Rr
    float* Rr = (float*)X;
#pragma unroll
    for (int cc = 0; cc < 8; ++cc) {
        int k = wv * 8 + cc;
        float2 r0 = c0[cc], r1 = c1[cc];
        float2 t = r0;
        r0 = cadd(t, r1);
        r1 = cmul(csub(t, r1), w64);
        r0 = fft64s(r0, w, sg);
        r1 = fft64s(r1, w, sg);
        Rr[(2 * b6) * 65 + k]     = r0.x;
        Rr[(2 * b6 + 1) * 65 + k] = r1.x;
    }
    __syncthreads();
    // ---- frequency-domain D4 symmetrization (ushort4 bf16 stores) ----
    ushort4* ko4 = (ushort4*)(kout + (size_t)img * 8192);
    for (int i = threadIdx.x; i < 2048; i += 512) {
        int n = i >> 4, k4 = (i & 15) << 2;
        float op[4];
#pragma unroll
        for (int m = 0; m < 4; ++m) {
            int k = k4 + m;
            float t1 = Rr[n * 65 + k];
            float t2 = Rr[((128 - n) & 127) * 65 + k];
            float t3, t4;
            if (n < 64) {
                t3 = Rr[k * 65 + n];
                t4 = Rr[((128 - k) & 127) * 65 + n];
            } else {
                int c2 = 128 - n; if (c2 > 63) c2 = 63;   // n==64 unused downstream
                t3 = Rr[((128 - k) & 127) * 65 + c2];
                t4 = Rr[k * 65 + c2];
            }
            op[m] = 0.25f * (t1 + t2 + t3 + t4);
        }
        ushort4 o4;
        o4.x = (ushort16)bfu(op[0]); o4.y = (ushort16)bfu(op[1]);
        o4.z = (ushort16)bfu(op[2]); o4.w = (ushort16)bfu(op[3]);
        ko4[i] = o4;
    }
}

// ---------------------------------------------------------------------------
// ffull body (one block per f-image, 8 waves): row rfft256 via cfft128 in
// regs (32 rows/wave) -> bf16 half-spectrum in LDS (swizzled, 67.6 KB, never
// hits HBM) -> col cfft256 (8 cols/wave) -> truncate to signed 128-row set,
// scale 0.25 -> bf16 FHAT.
// ---------------------------------------------------------------------------
__device__ void ffull_body(const float* __restrict__ f, uint32* __restrict__ FH,
                           uint32* S, int img) {
    int lane = threadIdx.x & 63, wv = threadIdx.x >> 6;   // 8 waves
    float2 w[6]; float sg[6];
    tw_init<false>(lane, w, sg);
    float sn, cs;
    __sincosf(-PI_F * (float)lane * (1.0f / 64.0f), &sn, &cs);
    float2 w64 = make_float2(cs, sn);
    int m = brev6(lane);
    __sincosf(-PI_F * (float)(2 * m) * (1.0f / 128.0f), &sn, &cs);
    float2 wue = make_float2(cs, sn);           // unpack twiddle, k = 2m
    __sincosf(-PI_F * (float)(2 * m + 1) * (1.0f / 128.0f), &sn, &cs);
    float2 wuo = make_float2(cs, sn);           // unpack twiddle, k = 2m+1
    int src_e = brev6((64 - m) & 63);           // lane holding Z[2*(64-m)] in r0
    int src_o = brev6(63 - m);                  // lane holding Z[2*(63-m)+1] in r1
    bool active = (lane & 1) == 0;              // m < 32
    const float* fimg = f + (size_t)img * 65536;
    // ---- row phase: 32 rows/wave, rfft256 via cfft128, bf16 -> LDS ----
#pragma unroll 2
    for (int rr = 0; rr < 32; ++rr) {
        int r = wv * 32 + rr;
        const float2* x = (const float2*)(fimg + r * 256);
        float2 r0 = x[lane], r1 = x[lane + 64];
        float2 t = r0;
        r0 = cadd(t, r1);
        r1 = cmul(csub(t, r1), w64);
        r0 = fft64s(r0, w, sg);                 // r0[l] = Z[2*brev6(l)]
        r1 = fft64s(r1, w, sg);                 // r1[l] = Z[2*brev6(l)+1]
        float2 zme = shfli(r0, src_e);          // Z[128-2m]
        float2 zmo = shfli(r1, src_o);          // Z[128-(2m+1)]
        float ar = r0.x + zme.x, ai = r0.y - zme.y;
        float br = r0.x - zme.x, bi = r0.y + zme.y;
        float p = wue.x * br - wue.y * bi, q = wue.x * bi + wue.y * br;
        uint32 xe = packbf2(make_float2(0.5f * (ar + q), 0.5f * (ai - p)));
        ar = r1.x + zmo.x; ai = r1.y - zmo.y;
        br = r1.x - zmo.x; bi = r1.y + zmo.y;
        p = wuo.x * br - wuo.y * bi; q = wuo.x * bi + wuo.y * br;
        uint32 xo = packbf2(make_float2(0.5f * (ar + q), 0.5f * (ai - p)));
        if (active) *(uint2*)&S[s66(r, 2 * m)] = make_uint2(xe, xo);
    }
    __syncthreads();
    // ---- col phase: cfft256 per column, 8 cols/wave in 4 chunks of 2.
    // Columns are wave-exclusive -> in-place, no intermediate barriers. ----
    __sincosf(-PI_F * (float)lane * (1.0f / 128.0f), &sn, &cs);
    float2 w128a = make_float2(cs, sn);
    __sincosf(-PI_F * (float)(lane + 64) * (1.0f / 128.0f), &sn, &cs);
    float2 w128b = make_float2(cs, sn);
    int b6 = brev6(lane);
#pragma unroll
    for (int ch = 0; ch < 4; ++ch) {
        float2 q0[2], q1[2], q2[2], q3[2];
#pragma unroll
        for (int cc = 0; cc < 2; ++cc) {
            int c = wv * 8 + ch * 2 + cc;
            q0[cc] = unpackbf2(S[s66(lane,       c)]);
            q1[cc] = unpackbf2(S[s66(lane +  64, c)]);
            q2[cc] = unpackbf2(S[s66(lane + 128, c)]);
            q3[cc] = unpackbf2(S[s66(lane + 192, c)]);
        }
#pragma unroll
        for (int cc = 0; cc < 2; ++cc) {
            int c = wv * 8 + ch * 2 + cc;
            float2 r0 = q0[cc], r1 = q1[cc], r2 = q2[cc], r3 = q3[cc], t;
            t = r0; r0 = cadd(t, r2); r2 = cmul(csub(t, r2), w128a);
            t = r1; r1 = cadd(t, r3); r3 = cmul(csub(t, r3), w128b);
            t = r0; r0 = cadd(t, r1); r1 = cmul(csub(t, r1), w64);
            t = r2; r2 = cadd(t, r3); r3 = cmul(csub(t, r3), w64);
            r0 = fft64s(r0, w, sg); r1 = fft64s(r1, w, sg);
            r2 = fft64s(r2, w, sg); r3 = fft64s(r3, w, sg);
            float2 vv[4] = { r0, r2, r1, r3 };  // n = 4*b6 + j (brev2 order)
#pragma unroll
            for (int j = 0; j < 4; ++j) {
                int n = 4 * b6 + j;
                int r = (n < 64) ? n : ((n >= 193) ? n - 128 : -1);
                if (r >= 0)
                    S[s66(r, c)] = packbf2(make_float2(vv[j].x * 0.25f, vv[j].y * 0.25f));
            }
        }
    }
    __syncthreads();
    // ---- coalesced FHAT store (row 64 zeroed) ----
    uint32* dst = FH + (size_t)img * 8192;
    for (int i = threadIdx.x; i < 8192; i += 512) {
        int r = i >> 6, c = i & 63;
        dst[i] = (r == 64) ? 0u : S[s66(r, c)];
    }
}

// ---------------------------------------------------------------------------
// L1: ffull (bid<128, heavy, scheduled first) || kfft (bid>=128)
// ---------------------------------------------------------------------------
__global__ __launch_bounds__(512) void mega_a(const float* __restrict__ kin,
                                              ushort16* __restrict__ Kr,
                                              const float* __restrict__ f,
                                              uint32* __restrict__ FH) {
    __shared__ uint32 SH[256 * 66];             // 67584 B (union: kfft uses 66560 B)
    int bid = blockIdx.x;
    if (bid < 128) ffull_body(f, FH, SH, bid);
    else           kfft_body(kin, Kr, (float2*)SH, bid - 128);
}

// ---------------------------------------------------------------------------
// ifuse core (8 waves): spectrum already in LDS S[128*65] -> col icfft128 in
// regs, row pack + icfft64 in regs -> 128x128 fp32 reals, scaled 1/8192.
// ---------------------------------------------------------------------------
__device__ void ifuse_core(float2* S, float2* __restrict__ dst) {
    int lane = threadIdx.x & 63, wv = threadIdx.x >> 6;   // 8 waves
    float2 w[6]; float sg[6];
    tw_init<true>(lane, w, sg);
    float sn, cs;
    __sincosf(PI_F * (float)lane * (1.0f / 64.0f), &sn, &cs);
    float2 w64 = make_float2(cs, sn);           // inverse intra-stage AND pack twiddle
    int b6 = brev6(lane);
    // col phase: 8 cols/wave; columns wave-exclusive -> in-place, no barrier
    // between reads and writes (wave-lockstep read-before-write per column).
#pragma unroll
    for (int cc = 0; cc < 8; ++cc) {
        int k = wv * 8 + cc;
        float2 r0 = S[lane * 65 + k];
        float2 r1 = S[(lane + 64) * 65 + k];
        float2 t = r0;
        r0 = cadd(t, r1);
        r1 = cmul(csub(t, r1), w64);
        r0 = fft64s(r0, w, sg);
        r1 = fft64s(r1, w, sg);
        S[(2 * b6) * 65 + k]     = r0;
        S[(2 * b6 + 1) * 65 + k] = r1;
    }
    __syncthreads();
    // ---- row phase: irfft128 via icfft64, 16 rows per wave ----
#pragma unroll 2
    for (int rr = 0; rr < 16; ++rr) {
        int m = wv * 16 + rr;
        float2 X = S[m * 65 + lane];
        float2 Xm = shfli(X, (64 - lane) & 63);
        if (lane == 0) Xm = make_float2(0.f, 0.f);   // X[64] == 0
        float er = 0.5f * (X.x + Xm.x), ei = 0.5f * (X.y - Xm.y);
        float br = 0.5f * (X.x - Xm.x), bi = 0.5f * (X.y + Xm.y);
        float orr = w64.x * br - w64.y * bi, oi = w64.x * bi + w64.y * br;
        float2 Z = make_float2(er - oi, ei + orr);
        Z = fft64s(Z, w, sg);                   // lane l holds z[brev6(l)]
        dst[m * 64 + b6] = make_float2(Z.x * (1.0f / 8192.0f), Z.y * (1.0f / 8192.0f));
    }
}

// ifuse from a bf16c spectrum in global memory (out0 path).
__device__ void ifuse_body(const uint32* __restrict__ src, float2* __restrict__ dst,
                           float2* S) {
    for (int i = threadIdx.x; i < 8192; i += 512) {
        int r = i >> 6, c = i & 63;
        S[r * 65 + c] = unpackbf2(src[i]);
    }
    __syncthreads();
    ifuse_core(S, dst);
}

// ---------------------------------------------------------------------------
// convifuse body: one (b,d) output image. Computes the einsum
// S[nk] = sum_c FHAT[b,c,nk] * Kr[c,d,nk] (K real bf16) directly into LDS
// (fp32, no bf16 round-trip through HBM), then iFFTs. FHAT (4 MB) and Kr
// (8 MB) are cache-resident -> the 16x re-reads are L2/L3 hits, not HBM.
// ---------------------------------------------------------------------------
__device__ void convifuse_body(const uint32* __restrict__ FH,
                               const uint32* __restrict__ Kr32,
                               float2* __restrict__ dst, float2* S, int img) {
    int b = img >> 5, d = img & 31;
    int t = threadIdx.x;
#pragma unroll 2
    for (int p = 0; p < 8; ++p) {
        int nk2 = (t + p * 512) * 2;            // even nk; pairs (nk2, nk2+1)
        float2 a0 = make_float2(0.f, 0.f), a1 = make_float2(0.f, 0.f);
#pragma unroll
        for (int c = 0; c < 16; ++c) {
            uint2  fv = *(const uint2*)&FH[((size_t)(b * 16 + c) << 13) + nk2];
            uint32 kv = Kr32[((size_t)(c * 32 + d) << 12) + (nk2 >> 1)];
            float2 kk = unpackbf2(kv);          // K[nk2], K[nk2+1] (real)
            float2 f0 = unpackbf2(fv.x), f1 = unpackbf2(fv.y);
            a0.x = fmaf(f0.x, kk.x, a0.x); a0.y = fmaf(f0.y, kk.x, a0.y);
            a1.x = fmaf(f1.x, kk.y, a1.x); a1.y = fmaf(f1.y, kk.y, a1.y);
        }
        int r = nk2 >> 6, cc = nk2 & 63;        // nk2 even -> nk2+1 same row
        S[r * 65 + cc]     = a0;
        S[r * 65 + cc + 1] = a1;
    }
    __syncthreads();
    ifuse_core(S, dst);
}

// ---------------------------------------------------------------------------
// L2: conv+ifuse out1 (bid<256, heavy) || ifuse out0 (bid>=256).
// No cross-dependency between the two halves -> single kernel, one launch.
// ---------------------------------------------------------------------------
__global__ __launch_bounds__(512) void mega_b(const uint32* __restrict__ FH,
                                              const uint32* __restrict__ Kr32,
                                              float* __restrict__ out) {
    __shared__ float2 SH[128 * 65];
    int bid = blockIdx.x;
    if (bid < 256) {
        int img = bid;                          // b*32+d -> out1
        convifuse_body(FH, Kr32, (float2*)(out + 2097152 + (size_t)img * 16384),
                       SH, img);
    } else {
        int img = bid - 256;                    // 0..127 -> out0
        ifuse_body(FH + (size_t)img * 8192, (float2*)(out + (size_t)img * 16384), SH);
    }
}

// ---------------------------------------------------------------------------
// Launch
// ---------------------------------------------------------------------------
extern "C" void kernel_launch(void* const* d_in, const int* in_sizes, int n_in,
                              void* d_out, int out_size, void* d_ws, size_t ws_size,
                              hipStream_t stream) {
    const float* f   = (const float*)d_in[0];   // (8,16,256,256)
    const float* kin = (const float*)d_in[1];   // (1,16,32,128,128)
    float* out = (float*)d_out;                 // (8,16,128,128) | (8,32,128,128)
    char* ws = (char*)d_ws;

    // workspace (bf16 intermediates):
    //   [8388608, 12582912)   : FHAT (128 x 8192 bf16c)
    //   [16777216, 25165824)  : Kr (512 x 8192 bf16)
    uint32*   FHAT = (uint32*)(ws + 8388608);
    ushort16* Kr   = (ushort16*)(ws + 16777216);

    mega_a<<<640, 512, 0, stream>>>(kin, Kr, f, FHAT);       // ffull || kfft
    mega_b<<<384, 512, 0, stream>>>(FHAT, (const uint32*)Kr, out);  // conv+ifuse
}

// Round 6
// 152.369 us; speedup vs baseline: 1.0864x; 1.0864x over previous
//
#include <hip/hip_runtime.h>

#define PI_F 3.14159265358979f

typedef unsigned int  uint32;
typedef unsigned short ushort16;

// ---------------------------------------------------------------------------
// complex / bf16 helpers
// ---------------------------------------------------------------------------
__device__ __forceinline__ float2 cmul(float2 a, float2 b) {
    return make_float2(a.x * b.x - a.y * b.y, a.x * b.y + a.y * b.x);
}
__device__ __forceinline__ float2 cadd(float2 a, float2 b) { return make_float2(a.x + b.x, a.y + b.y); }
__device__ __forceinline__ float2 csub(float2 a, float2 b) { return make_float2(a.x - b.x, a.y - b.y); }
__device__ __forceinline__ float2 shflx(float2 v, int m) {
    return make_float2(__shfl_xor(v.x, m, 64), __shfl_xor(v.y, m, 64));
}
__device__ __forceinline__ float2 shfli(float2 v, int src) {
    return make_float2(__shfl(v.x, src, 64), __shfl(v.y, src, 64));
}
__device__ __forceinline__ int brev6(int x) { return (int)(__brev((unsigned)x) >> 26); }

__device__ __forceinline__ uint32 bfu(float x) {              // fp32 -> bf16 (RNE), low 16
    uint32 u = __float_as_uint(x);
    return (u + 0x7FFFu + ((u >> 16) & 1u)) >> 16;
}
__device__ __forceinline__ uint32 packbf2(float2 v) { return bfu(v.x) | (bfu(v.y) << 16); }
__device__ __forceinline__ float2 unpackbf2(uint32 u) {
    return make_float2(__uint_as_float(u << 16), __uint_as_float(u & 0xFFFF0000u));
}
__device__ __forceinline__ float bf2f(ushort16 u) { return __uint_as_float((uint32)u << 16); }

// DPP cross-lane exchange (no LDS pipe): xor1 = quad_perm[1,0,3,2] (0xB1),
// xor2 = quad_perm[2,3,0,1] (0x4E), xor8 = row_ror:8 (0x128).
template<int CTRL>
__device__ __forceinline__ float dpp1(float x) {
    return __builtin_bit_cast(float, __builtin_amdgcn_update_dpp(
        0, __builtin_bit_cast(int, x), CTRL, 0xF, 0xF, true));
}
template<int CTRL>
__device__ __forceinline__ float2 dppx(float2 v) {
    return make_float2(dpp1<CTRL>(v.x), dpp1<CTRL>(v.y));
}

// ds_swizzle xor-4 (BitMode: xor_mask=4, and_mask=0x1F).
__device__ __forceinline__ float swz4(float x) {
    return __int_as_float(__builtin_amdgcn_ds_swizzle(__float_as_int(x), 0x101F));
}

// Per-lane twiddles for the 6 shuffle DIF stages (m = 32,16,8,4,2,1).
// Stages 0,1 (m=32,16): orientation-free permlane-swap butterfly
//   sg[t] = up ? -2 : 0,  d = (v[l|m] + v[l&~m]) + sg*v
// Stages 2..5: partner-exchange form: sg[t] = up ? -1 : +1, d = sg*v + p.
template<bool INV>
__device__ __forceinline__ void tw_init(int lane, float2* w, float* sg) {
#pragma unroll
    for (int t = 0; t < 6; ++t) {
        int m = 32 >> t;
        bool up = (lane & m) != 0;
        int pos = lane & (m - 1);
        float ang = (INV ? PI_F : -PI_F) * (float)pos / (float)m;
        float sn, cs;
        __sincosf(ang, &sn, &cs);
        w[t]  = up ? make_float2(cs, sn) : make_float2(1.f, 0.f);
        sg[t] = (t < 2) ? (up ? -2.f : 0.f) : (up ? -1.f : 1.f);
    }
}

// 64-pt DIF FFT across the wave, 1 elem/lane. Natural in; out: lane l holds X[brev6(l)].
__device__ __forceinline__ float2 fft64s(float2 v, const float2* w, const float* sg) {
#if __has_builtin(__builtin_amdgcn_permlane32_swap) && __has_builtin(__builtin_amdgcn_permlane16_swap)
    {   // stage 0: m=32 via permlane32_swap (VALU pipe)
        auto rx = __builtin_amdgcn_permlane32_swap(__float_as_uint(v.x), __float_as_uint(v.x), false, false);
        auto ry = __builtin_amdgcn_permlane32_swap(__float_as_uint(v.y), __float_as_uint(v.y), false, false);
        float2 d = make_float2(
            fmaf(sg[0], v.x, __uint_as_float(rx[0]) + __uint_as_float(rx[1])),
            fmaf(sg[0], v.y, __uint_as_float(ry[0]) + __uint_as_float(ry[1])));
        v = cmul(d, w[0]);
    }
    {   // stage 1: m=16 via permlane16_swap
        auto rx = __builtin_amdgcn_permlane16_swap(__float_as_uint(v.x), __float_as_uint(v.x), false, false);
        auto ry = __builtin_amdgcn_permlane16_swap(__float_as_uint(v.y), __float_as_uint(v.y), false, false);
        float2 d = make_float2(
            fmaf(sg[1], v.x, __uint_as_float(rx[0]) + __uint_as_float(rx[1])),
            fmaf(sg[1], v.y, __uint_as_float(ry[0]) + __uint_as_float(ry[1])));
        v = cmul(d, w[1]);
    }
#else
    {   float2 p = shflx(v, 32); float s0 = 1.0f + sg[0];
        float2 d = make_float2(fmaf(s0, v.x, p.x), fmaf(s0, v.y, p.y));
        v = cmul(d, w[0]);
    }
    {   float2 p = shflx(v, 16); float s1 = 1.0f + sg[1];
        float2 d = make_float2(fmaf(s1, v.x, p.x), fmaf(s1, v.y, p.y));
        v = cmul(d, w[1]);
    }
#endif
    {   // stage 2: m=8 (DPP row_ror:8)
        float2 p = dppx<0x128>(v);
        float2 d = make_float2(fmaf(sg[2], v.x, p.x), fmaf(sg[2], v.y, p.y));
        v = cmul(d, w[2]);
    }
    {   // stage 3: m=4 (ds_swizzle xor4)
        float2 p = make_float2(swz4(v.x), swz4(v.y));
        float2 d = make_float2(fmaf(sg[3], v.x, p.x), fmaf(sg[3], v.y, p.y));
        v = cmul(d, w[3]);
    }
    {   // stage 4: m=2 (DPP)
        float2 p = dppx<0x4E>(v);
        float2 d = make_float2(fmaf(sg[4], v.x, p.x), fmaf(sg[4], v.y, p.y));
        v = cmul(d, w[4]);
    }
    {   // stage 5: m=1 (DPP)
        float2 p = dppx<0xB1>(v);
        float2 d = make_float2(fmaf(sg[5], v.x, p.x), fmaf(sg[5], v.y, p.y));
        v = cmul(d, w[5]);
    }
    return v;
}

// XOR-swizzled LDS index for the 256x64 bf16c half-spectrum (stride 66 words).
__device__ __forceinline__ int s66(int r, int c) {
    return r * 66 + (c ^ (((r >> 4) & 3) << 4));
}

// ---------------------------------------------------------------------------
// kfft body (one block per (c1,c2) image, 8 waves): rfft2(128x128) in regs +
// frequency-domain D4 symmetrization -> real K (128 x 64) in bf16.
// ---------------------------------------------------------------------------
__device__ void kfft_body(const float* __restrict__ kin, ushort16* __restrict__ kout,
                          float2* X, int img) {
    int lane = threadIdx.x & 63, wv = threadIdx.x >> 6;   // 8 waves
    float2 w[6]; float sg[6];
    tw_init<false>(lane, w, sg);
    int b6 = brev6(lane);
    float sn, cs;
    __sincosf(-PI_F * (float)lane * (1.0f / 64.0f), &sn, &cs);
    float2 w64 = make_float2(cs, sn);           // col intra-stage twiddle (lane-based)
    __sincosf(-PI_F * (float)b6 * (1.0f / 64.0f), &sn, &cs);
    float2 wub = make_float2(cs, sn);           // rfft unpack twiddle at k = b6
    const float2* in2 = (const float2*)(kin + (size_t)img * 16384);
    int gm2 = brev6((64 - b6) & 63);            // lane holding Z[(64-b6)&63]
    // ---- row phase: 16 rows per wave, rfft128 via cfft64 in regs ----
#pragma unroll 2
    for (int rr = 0; rr < 16; ++rr) {
        int r = wv * 16 + rr;
        float2 z = in2[r * 64 + lane];
        z = fft64s(z, w, sg);                   // lane l holds Z[brev6(l)]
        float2 zm = shfli(z, gm2);
        float ar = z.x + zm.x, ai = z.y - zm.y;
        float br = z.x - zm.x, bi = z.y + zm.y;
        float p = wub.x * br - wub.y * bi, q = wub.x * bi + wub.y * br;
        X[r * 65 + b6] = make_float2(0.5f * (ar + q), 0.5f * (ai - p));
    }
    __syncthreads();
    // ---- col phase: 8 cols per wave, cfft128 (2 regs/lane) ----
    float2 c0[8], c1[8];
#pragma unroll
    for (int cc = 0; cc < 8; ++cc) {
        int k = wv * 8 + cc;
        c0[cc] = X[lane * 65 + k];
        c1[cc] = X[(lane + 64) * 65 + k];
    }
    __syncthreads();                            // all X reads done; reuse LDS as Rr
    float* Rr = (float*)X;
#pragma unroll
    for (int cc = 0; cc < 8; ++cc) {
        int k = wv * 8 + cc;
        float2 r0 = c0[cc], r1 = c1[cc];
        float2 t = r0;
        r0 = cadd(t, r1);
        r1 = cmul(csub(t, r1), w64);
        r0 = fft64s(r0, w, sg);
        r1 = fft64s(r1, w, sg);
        Rr[(2 * b6) * 65 + k]     = r0.x;
        Rr[(2 * b6 + 1) * 65 + k] = r1.x;
    }
    __syncthreads();
    // ---- frequency-domain D4 symmetrization (ushort4 bf16 stores) ----
    ushort4* ko4 = (ushort4*)(kout + (size_t)img * 8192);
    for (int i = threadIdx.x; i < 2048; i += 512) {
        int n = i >> 4, k4 = (i & 15) << 2;
        float op[4];
#pragma unroll
        for (int m = 0; m < 4; ++m) {
            int k = k4 + m;
            float t1 = Rr[n * 65 + k];
            float t2 = Rr[((128 - n) & 127) * 65 + k];
            float t3, t4;
            if (n < 64) {
                t3 = Rr[k * 65 + n];
                t4 = Rr[((128 - k) & 127) * 65 + n];
            } else {
                int c2 = 128 - n; if (c2 > 63) c2 = 63;   // n==64 unused downstream
                t3 = Rr[((128 - k) & 127) * 65 + c2];
                t4 = Rr[k * 65 + c2];
            }
            op[m] = 0.25f * (t1 + t2 + t3 + t4);
        }
        ushort4 o4;
        o4.x = (ushort16)bfu(op[0]); o4.y = (ushort16)bfu(op[1]);
        o4.z = (ushort16)bfu(op[2]); o4.w = (ushort16)bfu(op[3]);
        ko4[i] = o4;
    }
}

// ---------------------------------------------------------------------------
// ffull body (one block per f-image, 8 waves): row rfft256 via cfft128 in
// regs (32 rows/wave) -> bf16 half-spectrum in LDS (swizzled, 67.6 KB, never
// hits HBM) -> col cfft256 (8 cols/wave) -> truncate to signed 128-row set,
// scale 0.25 -> bf16 FHAT.
// ---------------------------------------------------------------------------
__device__ void ffull_body(const float* __restrict__ f, uint32* __restrict__ FH,
                           uint32* S, int img) {
    int lane = threadIdx.x & 63, wv = threadIdx.x >> 6;   // 8 waves
    float2 w[6]; float sg[6];
    tw_init<false>(lane, w, sg);
    float sn, cs;
    __sincosf(-PI_F * (float)lane * (1.0f / 64.0f), &sn, &cs);
    float2 w64 = make_float2(cs, sn);
    int m = brev6(lane);
    __sincosf(-PI_F * (float)(2 * m) * (1.0f / 128.0f), &sn, &cs);
    float2 wue = make_float2(cs, sn);           // unpack twiddle, k = 2m
    __sincosf(-PI_F * (float)(2 * m + 1) * (1.0f / 128.0f), &sn, &cs);
    float2 wuo = make_float2(cs, sn);           // unpack twiddle, k = 2m+1
    int src_e = brev6((64 - m) & 63);           // lane holding Z[2*(64-m)] in r0
    int src_o = brev6(63 - m);                  // lane holding Z[2*(63-m)+1] in r1
    bool active = (lane & 1) == 0;              // m < 32
    const float* fimg = f + (size_t)img * 65536;
    // ---- row phase: 32 rows/wave, rfft256 via cfft128, bf16 -> LDS ----
#pragma unroll 2
    for (int rr = 0; rr < 32; ++rr) {
        int r = wv * 32 + rr;
        const float2* x = (const float2*)(fimg + r * 256);
        float2 r0 = x[lane], r1 = x[lane + 64];
        float2 t = r0;
        r0 = cadd(t, r1);
        r1 = cmul(csub(t, r1), w64);
        r0 = fft64s(r0, w, sg);                 // r0[l] = Z[2*brev6(l)]
        r1 = fft64s(r1, w, sg);                 // r1[l] = Z[2*brev6(l)+1]
        float2 zme = shfli(r0, src_e);          // Z[128-2m]
        float2 zmo = shfli(r1, src_o);          // Z[128-(2m+1)]
        float ar = r0.x + zme.x, ai = r0.y - zme.y;
        float br = r0.x - zme.x, bi = r0.y + zme.y;
        float p = wue.x * br - wue.y * bi, q = wue.x * bi + wue.y * br;
        uint32 xe = packbf2(make_float2(0.5f * (ar + q), 0.5f * (ai - p)));
        ar = r1.x + zmo.x; ai = r1.y - zmo.y;
        br = r1.x - zmo.x; bi = r1.y + zmo.y;
        p = wuo.x * br - wuo.y * bi; q = wuo.x * bi + wuo.y * br;
        uint32 xo = packbf2(make_float2(0.5f * (ar + q), 0.5f * (ai - p)));
        if (active) *(uint2*)&S[s66(r, 2 * m)] = make_uint2(xe, xo);
    }
    __syncthreads();
    // ---- col phase: cfft256 per column, 8 cols/wave in 4 chunks of 2.
    // Columns are wave-exclusive -> in-place, no intermediate barriers. ----
    __sincosf(-PI_F * (float)lane * (1.0f / 128.0f), &sn, &cs);
    float2 w128a = make_float2(cs, sn);
    __sincosf(-PI_F * (float)(lane + 64) * (1.0f / 128.0f), &sn, &cs);
    float2 w128b = make_float2(cs, sn);
    int b6 = brev6(lane);
#pragma unroll
    for (int ch = 0; ch < 4; ++ch) {
        float2 q0[2], q1[2], q2[2], q3[2];
#pragma unroll
        for (int cc = 0; cc < 2; ++cc) {
            int c = wv * 8 + ch * 2 + cc;
            q0[cc] = unpackbf2(S[s66(lane,       c)]);
            q1[cc] = unpackbf2(S[s66(lane +  64, c)]);
            q2[cc] = unpackbf2(S[s66(lane + 128, c)]);
            q3[cc] = unpackbf2(S[s66(lane + 192, c)]);
        }
#pragma unroll
        for (int cc = 0; cc < 2; ++cc) {
            int c = wv * 8 + ch * 2 + cc;
            float2 r0 = q0[cc], r1 = q1[cc], r2 = q2[cc], r3 = q3[cc], t;
            t = r0; r0 = cadd(t, r2); r2 = cmul(csub(t, r2), w128a);
            t = r1; r1 = cadd(t, r3); r3 = cmul(csub(t, r3), w128b);
            t = r0; r0 = cadd(t, r1); r1 = cmul(csub(t, r1), w64);
            t = r2; r2 = cadd(t, r3); r3 = cmul(csub(t, r3), w64);
            r0 = fft64s(r0, w, sg); r1 = fft64s(r1, w, sg);
            r2 = fft64s(r2, w, sg); r3 = fft64s(r3, w, sg);
            float2 vv[4] = { r0, r2, r1, r3 };  // n = 4*b6 + j (brev2 order)
#pragma unroll
            for (int j = 0; j < 4; ++j) {
                int n = 4 * b6 + j;
                int r = (n < 64) ? n : ((n >= 193) ? n - 128 : -1);
                if (r >= 0)
                    S[s66(r, c)] = packbf2(make_float2(vv[j].x * 0.25f, vv[j].y * 0.25f));
            }
        }
    }
    __syncthreads();
    // ---- coalesced FHAT store (row 64 zeroed) ----
    uint32* dst = FH + (size_t)img * 8192;
    for (int i = threadIdx.x; i < 8192; i += 512) {
        int r = i >> 6, c = i & 63;
        dst[i] = (r == 64) ? 0u : S[s66(r, c)];
    }
}

// ---------------------------------------------------------------------------
// L1: ffull (bid<128, heavy, scheduled first) || kfft (bid>=128)
// ---------------------------------------------------------------------------
__global__ __launch_bounds__(512) void mega_a(const float* __restrict__ kin,
                                              ushort16* __restrict__ Kr,
                                              const float* __restrict__ f,
                                              uint32* __restrict__ FH) {
    __shared__ uint32 SH[256 * 66];             // 67584 B (union: kfft uses 66560 B)
    int bid = blockIdx.x;
    if (bid < 128) ffull_body(f, FH, SH, bid);
    else           kfft_body(kin, Kr, (float2*)SH, bid - 128);
}

// ---------------------------------------------------------------------------
// L2: einsum only. C[b,d,nk] = sum_c F[b,c,nk] * K[c,d,nk] (K real bf16).
// One 32-nk group per block, 512 threads. F staged packed in LDS (16 KB).
// Small LDS/low duration; runs alone so the ifuse batch can be one kernel.
// ---------------------------------------------------------------------------
__global__ __launch_bounds__(512) void einsum_k(const uint32* __restrict__ F,
                                                const ushort16* __restrict__ K,
                                                uint32* __restrict__ C) {
    __shared__ uint32 Ft[4096];
    int bid = blockIdx.x;
    int nk0 = bid * 32;
    int t = threadIdx.x;
    for (int i = t; i < 4096; i += 512) {
        int bc = i >> 5, nl = i & 31;
        Ft[i] = F[(size_t)bc * 8192 + nk0 + nl];
    }
    __syncthreads();
    int nl = t & 31, dg = t >> 5;               // dg 0..15
    int nk = nk0 + nl;
    float2 acc[2][8] = {};
#pragma unroll
    for (int c = 0; c < 16; ++c) {
        float2 fv[8];
#pragma unroll
        for (int b = 0; b < 8; ++b) fv[b] = unpackbf2(Ft[(b * 16 + c) * 32 + nl]);
#pragma unroll
        for (int j = 0; j < 2; ++j) {
            int d = j * 16 + dg;
            float kv = bf2f(K[(size_t)(c * 32 + d) * 8192 + nk]);
#pragma unroll
            for (int b = 0; b < 8; ++b) {
                acc[j][b].x = fmaf(fv[b].x, kv, acc[j][b].x);
                acc[j][b].y = fmaf(fv[b].y, kv, acc[j][b].y);
            }
        }
    }
#pragma unroll
    for (int j = 0; j < 2; ++j) {
        int d = j * 16 + dg;
#pragma unroll
        for (int b = 0; b < 8; ++b)
            C[(size_t)(b * 32 + d) * 8192 + nk] = packbf2(acc[j][b]);
    }
}

// ---------------------------------------------------------------------------
// ifuse body (one output image, bf16 input, 8 waves): col icfft128 in regs,
// row pack + icfft64 in regs -> 128x128 fp32 reals, scaled 1/8192.
// ---------------------------------------------------------------------------
__device__ void ifuse_body(const uint32* __restrict__ src, float2* __restrict__ dst,
                           float2* S) {
    int lane = threadIdx.x & 63, wv = threadIdx.x >> 6;   // 8 waves
    float2 w[6]; float sg[6];
    tw_init<true>(lane, w, sg);
    float sn, cs;
    __sincosf(PI_F * (float)lane * (1.0f / 64.0f), &sn, &cs);
    float2 w64 = make_float2(cs, sn);           // inverse intra-stage AND pack twiddle
    for (int i = threadIdx.x; i < 8192; i += 512) {
        int r = i >> 6, c = i & 63;
        S[r * 65 + c] = unpackbf2(src[i]);
    }
    __syncthreads();
    int b6 = brev6(lane);
    // col phase: 8 cols/wave; columns wave-exclusive -> in-place, no barrier
    // between reads and writes (wave-lockstep read-before-write per column).
#pragma unroll
    for (int cc = 0; cc < 8; ++cc) {
        int k = wv * 8 + cc;
        float2 r0 = S[lane * 65 + k];
        float2 r1 = S[(lane + 64) * 65 + k];
        float2 t = r0;
        r0 = cadd(t, r1);
        r1 = cmul(csub(t, r1), w64);
        r0 = fft64s(r0, w, sg);
        r1 = fft64s(r1, w, sg);
        S[(2 * b6) * 65 + k]     = r0;
        S[(2 * b6 + 1) * 65 + k] = r1;
    }
    __syncthreads();
    // ---- row phase: irfft128 via icfft64, 16 rows per wave ----
#pragma unroll 2
    for (int rr = 0; rr < 16; ++rr) {
        int m = wv * 16 + rr;
        float2 X = S[m * 65 + lane];
        float2 Xm = shfli(X, (64 - lane) & 63);
        if (lane == 0) Xm = make_float2(0.f, 0.f);   // X[64] == 0
        float er = 0.5f * (X.x + Xm.x), ei = 0.5f * (X.y - Xm.y);
        float br = 0.5f * (X.x - Xm.x), bi = 0.5f * (X.y + Xm.y);
        float orr = w64.x * br - w64.y * bi, oi = w64.x * bi + w64.y * br;
        float2 Z = make_float2(er - oi, ei + orr);
        Z = fft64s(Z, w, sg);                   // lane l holds z[brev6(l)]
        dst[m * 64 + b6] = make_float2(Z.x * (1.0f / 8192.0f), Z.y * (1.0f / 8192.0f));
    }
}

// ---------------------------------------------------------------------------
// L3: ALL 384 inverse FFTs in one kernel (out1 from CONV, out0 from FHAT).
// All blocks co-resident (2 blocks/CU at 66.5 KB LDS) -> the two former
// serial ifuse passes overlap.
// ---------------------------------------------------------------------------
__global__ __launch_bounds__(512) void ifuse_all(const uint32* __restrict__ FH,
                                                 const uint32* __restrict__ CV,
                                                 float* __restrict__ out) {
    __shared__ float2 SH[128 * 65];
    int bid = blockIdx.x;
    if (bid < 256) {
        int img = bid;                          // 0..255 -> out1
        ifuse_body(CV + (size_t)img * 8192,
                   (float2*)(out + 2097152 + (size_t)img * 16384), SH);
    } else {
        int img = bid - 256;                    // 0..127 -> out0
        ifuse_body(FH + (size_t)img * 8192,
                   (float2*)(out + (size_t)img * 16384), SH);
    }
}

// ---------------------------------------------------------------------------
// Launch
// ---------------------------------------------------------------------------
extern "C" void kernel_launch(void* const* d_in, const int* in_sizes, int n_in,
                              void* d_out, int out_size, void* d_ws, size_t ws_size,
                              hipStream_t stream) {
    const float* f   = (const float*)d_in[0];   // (8,16,256,256)
    const float* kin = (const float*)d_in[1];   // (1,16,32,128,128)
    float* out = (float*)d_out;                 // (8,16,128,128) | (8,32,128,128)
    char* ws = (char*)d_ws;

    // workspace (bf16 intermediates):
    //   [0, 8388608)          : CONV (256 x 8192 bf16c)
    //   [8388608, 12582912)   : FHAT (128 x 8192 bf16c)
    //   [16777216, 25165824)  : Kr (512 x 8192 bf16)
    uint32*   CONV = (uint32*)ws;
    uint32*   FHAT = (uint32*)(ws + 8388608);
    ushort16* Kr   = (ushort16*)(ws + 16777216);

    mega_a<<<640, 512, 0, stream>>>(kin, Kr, f, FHAT);       // ffull || kfft
    einsum_k<<<256, 512, 0, stream>>>(FHAT, Kr, CONV);       // conv einsum
    ifuse_all<<<384, 512, 0, stream>>>(FHAT, CONV, out);     // all 384 iFFTs
}